// Round 1
// baseline (652.598 us; speedup 1.0000x reference)
//
#include <hip/hip_runtime.h>

#define NROWS 8192  // BT * N = 8 * 1024

// ---------------------------------------------------------------------------
// K1: LayerNorm over D=256 + transpose to K-major xnT[d][bt*1024+n]
// x layout: (B=2, D=256, T=4, H*W=1024). Coalesced along n; each thread owns
// one full row (loops d), so no cross-thread reduction needed.
// ---------------------------------------------------------------------------
__global__ __launch_bounds__(256) void ln_kernel(const float* __restrict__ x,
                                                 const float* __restrict__ gamma,
                                                 const float* __restrict__ beta,
                                                 float* __restrict__ xnT) {
  const int bx = blockIdx.x;         // 32 blocks: bt(8) x n-chunk(4)
  const int bt = bx >> 2;
  const int b = bt >> 2, t = bt & 3;
  const int n = ((bx & 3) << 8) + threadIdx.x;  // 0..1023
  const float* xp = x + ((size_t)(b * 256) * 4 + t) * 1024 + n;  // d stride = 4096
  float sum = 0.f, sumsq = 0.f;
#pragma unroll 8
  for (int d = 0; d < 256; ++d) {
    float vv = xp[(size_t)d * 4096];
    sum += vv;
    sumsq += vv * vv;
  }
  const float mu = sum * (1.0f / 256.0f);
  const float var = sumsq * (1.0f / 256.0f) - mu * mu;
  const float rstd = rsqrtf(var + 1e-6f);
  float* outp = xnT + (size_t)bt * 1024 + n;
#pragma unroll 8
  for (int d = 0; d < 256; ++d) {
    float vv = xp[(size_t)d * 4096];
    outp[(size_t)d * NROWS] = (vv - mu) * rstd * gamma[d] + beta[d];
  }
}

// ---------------------------------------------------------------------------
// K2: 5 projections fused via grid.z. C[m][o] = sum_d xnT[d][m] * W[o][d].
// Tiles 64x64, BK=16, 4x4 micro-tile per thread, 256 threads.
// Output layout (bt, head, n, dh): ((bt*8+head)*1024+n)*32+dh. q gets bias.
// ---------------------------------------------------------------------------
__global__ __launch_bounds__(256) void proj_kernel(
    const float* __restrict__ xnT,
    const float* __restrict__ Wq, const float* __restrict__ Wk,
    const float* __restrict__ Wv, const float* __restrict__ Wkl,
    const float* __restrict__ Wvl, const float* __restrict__ qb,
    float* __restrict__ qo, float* __restrict__ ko, float* __restrict__ vo,
    float* __restrict__ klo, float* __restrict__ vlo) {
  __shared__ float As[16][64];   // [k][m], reads 2-way aliased (free)
  __shared__ float Bs[16][68];   // [k][o], +4 pad keeps 16B alignment
  const int z = blockIdx.z;
  const float* Wm = (z == 0) ? Wq : (z == 1) ? Wk : (z == 2) ? Wv : (z == 3) ? Wkl : Wvl;
  float* Cm = (z == 0) ? qo : (z == 1) ? ko : (z == 2) ? vo : (z == 3) ? klo : vlo;
  const int m0 = blockIdx.x * 64;
  const int o0 = blockIdx.y * 64;
  const int tid = threadIdx.x;
  const int tx = tid & 15, ty = tid >> 4;
  float c[4][4] = {};
#pragma unroll 1
  for (int k0 = 0; k0 < 256; k0 += 16) {
    const int ml = tid & 63, kl4 = tid >> 6;
#pragma unroll
    for (int r = 0; r < 4; ++r)
      As[kl4 + r * 4][ml] = xnT[(size_t)(k0 + kl4 + r * 4) * NROWS + m0 + ml];
    const int kb = tid & 15, ob = tid >> 4;
#pragma unroll
    for (int r = 0; r < 4; ++r)
      Bs[kb][ob + r * 16] = Wm[(size_t)(o0 + ob + r * 16) * 256 + k0 + kb];
    __syncthreads();
#pragma unroll
    for (int kk = 0; kk < 16; ++kk) {
      const float4 a4 = *(const float4*)&As[kk][tx * 4];
      const float4 b4 = *(const float4*)&Bs[kk][ty * 4];
      const float a[4] = {a4.x, a4.y, a4.z, a4.w};
      const float b[4] = {b4.x, b4.y, b4.z, b4.w};
#pragma unroll
      for (int i = 0; i < 4; ++i)
#pragma unroll
        for (int j = 0; j < 4; ++j) c[i][j] += a[i] * b[j];
    }
    __syncthreads();
  }
#pragma unroll
  for (int i = 0; i < 4; ++i) {
    const int m = m0 + tx * 4 + i;
    const int bt = m >> 10, n = m & 1023;
#pragma unroll
    for (int j = 0; j < 4; ++j) {
      const int o = o0 + ty * 4 + j;
      float val = c[i][j];
      if (z == 0) val += qb[o];  // q_bias flat [head][dh] == o
      Cm[((size_t)(bt * 8 + (o >> 5)) * 1024 + n) * 32 + (o & 31)] = val;
    }
  }
}

// ---------------------------------------------------------------------------
// K3: flash attention, global (1024 keys) + 3x3 local, concat softmax.
// 1 wave per block, 1 query row per lane. factor*log2e folded into q regs.
// LDS row stride 36 floats: 16B-aligned float4, reads are broadcast.
// ---------------------------------------------------------------------------
__global__ __launch_bounds__(64) void attn_kernel(
    const float* __restrict__ q, const float* __restrict__ k,
    const float* __restrict__ v, const float* __restrict__ klp,
    const float* __restrict__ vlp, float* __restrict__ ctx) {
  __shared__ float kbuf[64 * 36];
  __shared__ float vbuf[64 * 36];
  const int qt = blockIdx.x;   // 16 query tiles
  const int bth = blockIdx.y;  // 64 = bt*8+head
  const int lane = threadIdx.x;
  const int n = qt * 64 + lane;
  const float SCALE = 0.17677669529663687f * 1.4426950408889634f;  // dh^-0.5 * log2(e)
  float qr[32];
  {
    const float4* qp = (const float4*)(q + ((size_t)bth * 1024 + n) * 32);
#pragma unroll
    for (int f = 0; f < 8; ++f) {
      float4 tq = qp[f];
      qr[f * 4 + 0] = tq.x * SCALE; qr[f * 4 + 1] = tq.y * SCALE;
      qr[f * 4 + 2] = tq.z * SCALE; qr[f * 4 + 3] = tq.w * SCALE;
    }
  }
  float acc[32];
#pragma unroll
  for (int d = 0; d < 32; ++d) acc[d] = 0.f;
  float m2 = -1e30f, l = 0.f;

#pragma unroll 1
  for (int kt = 0; kt < 16; ++kt) {
    __syncthreads();
    {
      const float4* kp = (const float4*)(k + ((size_t)bth * 1024 + kt * 64 + lane) * 32);
      const float4* vp = (const float4*)(v + ((size_t)bth * 1024 + kt * 64 + lane) * 32);
      float4* kd = (float4*)&kbuf[lane * 36];
      float4* vd = (float4*)&vbuf[lane * 36];
#pragma unroll
      for (int f = 0; f < 8; ++f) { kd[f] = kp[f]; vd[f] = vp[f]; }
    }
    __syncthreads();
    float s2[64];
#pragma unroll
    for (int j = 0; j < 64; ++j) {
      const float4* kr = (const float4*)&kbuf[j * 36];
      float s = 0.f;
#pragma unroll
      for (int f = 0; f < 8; ++f) {
        float4 kv = kr[f];
        s += qr[f * 4 + 0] * kv.x + qr[f * 4 + 1] * kv.y +
             qr[f * 4 + 2] * kv.z + qr[f * 4 + 3] * kv.w;
      }
      s2[j] = s;
    }
    float tm = -1e30f;
#pragma unroll
    for (int j = 0; j < 64; ++j) tm = fmaxf(tm, s2[j]);
    const float mnew = fmaxf(m2, tm);
    const float alpha = __builtin_amdgcn_exp2f(m2 - mnew);
    m2 = mnew;
    l *= alpha;
#pragma unroll
    for (int d = 0; d < 32; ++d) acc[d] *= alpha;
#pragma unroll
    for (int j = 0; j < 64; ++j) {
      const float p = __builtin_amdgcn_exp2f(s2[j] - mnew);
      l += p;
      const float4* vr = (const float4*)&vbuf[j * 36];
#pragma unroll
      for (int f = 0; f < 8; ++f) {
        float4 vv = vr[f];
        acc[f * 4 + 0] += p * vv.x; acc[f * 4 + 1] += p * vv.y;
        acc[f * 4 + 2] += p * vv.z; acc[f * 4 + 3] += p * vv.w;
      }
    }
  }

  // local 3x3 neighborhood as the final softmax tile
  {
    const int pi = n >> 5, pj = n & 31;
    float sl[9];
#pragma unroll
    for (int tt = 0; tt < 9; ++tt) {
      const int ni = pi + tt / 3 - 1;
      const int nj = pj + tt % 3 - 1;
      const bool ok = (ni >= 0) && (ni < 32) && (nj >= 0) && (nj < 32);
      float s = -1e30f;
      if (ok) {
        const float4* kr = (const float4*)(klp + ((size_t)bth * 1024 + ni * 32 + nj) * 32);
        s = 0.f;
#pragma unroll
        for (int f = 0; f < 8; ++f) {
          float4 kv = kr[f];
          s += qr[f * 4 + 0] * kv.x + qr[f * 4 + 1] * kv.y +
               qr[f * 4 + 2] * kv.z + qr[f * 4 + 3] * kv.w;
        }
      }
      sl[tt] = s;
    }
    float tm = -1e30f;
#pragma unroll
    for (int tt = 0; tt < 9; ++tt) tm = fmaxf(tm, sl[tt]);
    const float mnew = fmaxf(m2, tm);
    const float alpha = __builtin_amdgcn_exp2f(m2 - mnew);
    m2 = mnew;
    l *= alpha;
#pragma unroll
    for (int d = 0; d < 32; ++d) acc[d] *= alpha;
#pragma unroll
    for (int tt = 0; tt < 9; ++tt) {
      const int ni = pi + tt / 3 - 1;
      const int nj = pj + tt % 3 - 1;
      const bool ok = (ni >= 0) && (ni < 32) && (nj >= 0) && (nj < 32);
      if (ok) {
        const float p = __builtin_amdgcn_exp2f(sl[tt] - mnew);
        l += p;
        const float4* vr = (const float4*)(vlp + ((size_t)bth * 1024 + ni * 32 + nj) * 32);
#pragma unroll
        for (int f = 0; f < 8; ++f) {
          float4 vv = vr[f];
          acc[f * 4 + 0] += p * vv.x; acc[f * 4 + 1] += p * vv.y;
          acc[f * 4 + 2] += p * vv.z; acc[f * 4 + 3] += p * vv.w;
        }
      }
    }
  }

  const float inv = 1.0f / l;
  const int bt = bth >> 3, head = bth & 7;
  float* op = ctx + (((size_t)bt * 1024 + n) * 8 + head) * 32;  // (BT,N,D) head-major
#pragma unroll
  for (int f = 0; f < 8; ++f) {
    float4 o;
    o.x = acc[f * 4 + 0] * inv; o.y = acc[f * 4 + 1] * inv;
    o.z = acc[f * 4 + 2] * inv; o.w = acc[f * 4 + 3] * inv;
    ((float4*)op)[f] = o;
  }
}

// ---------------------------------------------------------------------------
// K4: out = ctx(8192x256) @ Wo^T, stored as (B, D, T, H*W) with n contiguous.
// ---------------------------------------------------------------------------
__global__ __launch_bounds__(256) void outproj_kernel(const float* __restrict__ ctx,
                                                      const float* __restrict__ Wo,
                                                      float* __restrict__ out) {
  __shared__ float As[16][68];  // [k][m]
  __shared__ float Bs[16][68];  // [k][o]
  const int m0 = blockIdx.x * 64;
  const int o0 = blockIdx.y * 64;
  const int tid = threadIdx.x;
  const int tx = tid & 15, ty = tid >> 4;
  float c[4][4] = {};
#pragma unroll 1
  for (int k0 = 0; k0 < 256; k0 += 16) {
    const int kb = tid & 15, rb = tid >> 4;
#pragma unroll
    for (int r = 0; r < 4; ++r) {
      As[kb][rb + r * 16] = ctx[(size_t)(m0 + rb + r * 16) * 256 + k0 + kb];
      Bs[kb][rb + r * 16] = Wo[(size_t)(o0 + rb + r * 16) * 256 + k0 + kb];
    }
    __syncthreads();
#pragma unroll
    for (int kk = 0; kk < 16; ++kk) {
      const float4 a4 = *(const float4*)&As[kk][tx * 4];
      const float4 b4 = *(const float4*)&Bs[kk][ty * 4];
      const float a[4] = {a4.x, a4.y, a4.z, a4.w};
      const float b[4] = {b4.x, b4.y, b4.z, b4.w};
#pragma unroll
      for (int i = 0; i < 4; ++i)
#pragma unroll
        for (int j = 0; j < 4; ++j) c[i][j] += a[i] * b[j];
    }
    __syncthreads();
  }
#pragma unroll
  for (int i = 0; i < 4; ++i) {
    const int m = m0 + tx * 4 + i;
    const int bt = m >> 10, n = m & 1023;
    const int b = bt >> 2, t = bt & 3;
#pragma unroll
    for (int j = 0; j < 4; ++j) {
      const int o = o0 + ty * 4 + j;
      out[((size_t)(b * 256 + o) * 4 + t) * 1024 + n] = c[i][j];
    }
  }
}

extern "C" void kernel_launch(void* const* d_in, const int* in_sizes, int n_in,
                              void* d_out, int out_size, void* d_ws, size_t ws_size,
                              hipStream_t stream) {
  const float* x = (const float*)d_in[0];
  const float* gamma = (const float*)d_in[1];
  const float* beta = (const float*)d_in[2];
  const float* Wq = (const float*)d_in[3];
  const float* Wk = (const float*)d_in[4];
  const float* Wv = (const float*)d_in[5];
  const float* Wkl = (const float*)d_in[6];
  const float* Wvl = (const float*)d_in[7];
  const float* Wo = (const float*)d_in[8];
  const float* qb = (const float*)d_in[9];

  float* ws = (float*)d_ws;
  const size_t SZ = (size_t)NROWS * 256;  // 2M floats = 8 MB
  float* xnT = ws;
  float* q = ws + SZ;
  float* k = ws + 2 * SZ;
  float* v = ws + 3 * SZ;
  float* kl = ws + 4 * SZ;
  float* vl = ws + 5 * SZ;
  float* ctx = ws + 6 * SZ;  // total 56 MB of workspace

  hipLaunchKernelGGL(ln_kernel, dim3(32), dim3(256), 0, stream, x, gamma, beta, xnT);
  hipLaunchKernelGGL(proj_kernel, dim3(128, 4, 5), dim3(256), 0, stream, xnT, Wq,
                     Wk, Wv, Wkl, Wvl, qb, q, k, v, kl, vl);
  hipLaunchKernelGGL(attn_kernel, dim3(16, 64), dim3(64), 0, stream, q, k, v, kl,
                     vl, ctx);
  hipLaunchKernelGGL(outproj_kernel, dim3(128, 4), dim3(256), 0, stream, ctx, Wo,
                     (float*)d_out);
}

// Round 2
// 397.940 us; speedup vs baseline: 1.6399x; 1.6399x over previous
//
#include <hip/hip_runtime.h>

#define NROWS 8192  // BT * N = 8 * 1024

// ---------------------------------------------------------------------------
// K1: LayerNorm over D=256 + transpose to K-major xnT[d][bt*1024+n]
// 128 blocks x 256 thr; block = 64 rows; wave `part` covers d-quarter.
// ---------------------------------------------------------------------------
__global__ __launch_bounds__(256) void ln_kernel(const float* __restrict__ x,
                                                 const float* __restrict__ gamma,
                                                 const float* __restrict__ beta,
                                                 float* __restrict__ xnT) {
  __shared__ float red[2][4][64];
  const int blk = blockIdx.x;  // 128 = bt(8) x nchunk(16)
  const int bt = blk >> 4;
  const int b = bt >> 2, t = bt & 3;
  const int n0 = (blk & 15) << 6;
  const int part = threadIdx.x >> 6, r = threadIdx.x & 63;
  const int n = n0 + r;
  const float* xp = x + ((size_t)(b * 256) * 4 + t) * 1024 + n;  // d stride 4096
  float sum = 0.f, sumsq = 0.f;
#pragma unroll 8
  for (int dd = 0; dd < 64; ++dd) {
    float vv = xp[(size_t)(part * 64 + dd) * 4096];
    sum += vv;
    sumsq += vv * vv;
  }
  red[0][part][r] = sum;
  red[1][part][r] = sumsq;
  __syncthreads();
  const float s1 = red[0][0][r] + red[0][1][r] + red[0][2][r] + red[0][3][r];
  const float s2 = red[1][0][r] + red[1][1][r] + red[1][2][r] + red[1][3][r];
  const float mu = s1 * (1.0f / 256.0f);
  const float var = s2 * (1.0f / 256.0f) - mu * mu;
  const float rstd = rsqrtf(var + 1e-6f);
  float* outp = xnT + (size_t)bt * 1024 + n;
#pragma unroll 8
  for (int dd = 0; dd < 64; ++dd) {
    const int d = part * 64 + dd;
    float vv = xp[(size_t)d * 4096];
    outp[(size_t)d * NROWS] = (vv - mu) * rstd * gamma[d] + beta[d];
  }
}

// ---------------------------------------------------------------------------
// K2: 5 projections fused via grid.z. C[m][o] = sum_d xnT[d][m] * W[o][d].
// ---------------------------------------------------------------------------
__global__ __launch_bounds__(256) void proj_kernel(
    const float* __restrict__ xnT,
    const float* __restrict__ Wq, const float* __restrict__ Wk,
    const float* __restrict__ Wv, const float* __restrict__ Wkl,
    const float* __restrict__ Wvl, const float* __restrict__ qb,
    float* __restrict__ qo, float* __restrict__ ko, float* __restrict__ vo,
    float* __restrict__ klo, float* __restrict__ vlo) {
  __shared__ float As[16][64];
  __shared__ float Bs[16][68];
  const int z = blockIdx.z;
  const float* Wm = (z == 0) ? Wq : (z == 1) ? Wk : (z == 2) ? Wv : (z == 3) ? Wkl : Wvl;
  float* Cm = (z == 0) ? qo : (z == 1) ? ko : (z == 2) ? vo : (z == 3) ? klo : vlo;
  const int m0 = blockIdx.x * 64;
  const int o0 = blockIdx.y * 64;
  const int tid = threadIdx.x;
  const int tx = tid & 15, ty = tid >> 4;
  float c[4][4] = {};
#pragma unroll 1
  for (int k0 = 0; k0 < 256; k0 += 16) {
    const int ml = tid & 63, kl4 = tid >> 6;
#pragma unroll
    for (int r = 0; r < 4; ++r)
      As[kl4 + r * 4][ml] = xnT[(size_t)(k0 + kl4 + r * 4) * NROWS + m0 + ml];
    const int kb = tid & 15, ob = tid >> 4;
#pragma unroll
    for (int r = 0; r < 4; ++r)
      Bs[kb][ob + r * 16] = Wm[(size_t)(o0 + ob + r * 16) * 256 + k0 + kb];
    __syncthreads();
#pragma unroll
    for (int kk = 0; kk < 16; ++kk) {
      const float4 a4 = *(const float4*)&As[kk][tx * 4];
      const float4 b4 = *(const float4*)&Bs[kk][ty * 4];
      const float a[4] = {a4.x, a4.y, a4.z, a4.w};
      const float b[4] = {b4.x, b4.y, b4.z, b4.w};
#pragma unroll
      for (int i = 0; i < 4; ++i)
#pragma unroll
        for (int j = 0; j < 4; ++j) c[i][j] += a[i] * b[j];
    }
    __syncthreads();
  }
#pragma unroll
  for (int i = 0; i < 4; ++i) {
    const int m = m0 + tx * 4 + i;
    const int bt = m >> 10, n = m & 1023;
#pragma unroll
    for (int j = 0; j < 4; ++j) {
      const int o = o0 + ty * 4 + j;
      float val = c[i][j];
      if (z == 0) val += qb[o];
      Cm[((size_t)(bt * 8 + (o >> 5)) * 1024 + n) * 32 + (o & 31)] = val;
    }
  }
}

// ---------------------------------------------------------------------------
// K3: flash attention, split-K across 4 waves of a 256-thread block.
// Wave w: keys [w*256, w*256+256) in 8 tiles of 32, wave-private LDS staging,
// NO barriers in the main loop. Wave 3 also handles the 3x3 local tile.
// End: online-softmax merge of the 4 partials via LDS.
// ---------------------------------------------------------------------------
#define TK 32
__global__ __launch_bounds__(256) void attn_kernel(
    const float* __restrict__ q, const float* __restrict__ k,
    const float* __restrict__ v, const float* __restrict__ klp,
    const float* __restrict__ vlp, float* __restrict__ ctx) {
  __shared__ float smem[9216];  // 36,864B: staging [w][2][TK*36]; combine overlays
  const int qt = blockIdx.x;    // 16 query tiles
  const int bth = blockIdx.y;   // 64 = bt*8+head
  const int tid = threadIdx.x;
  const int w = tid >> 6, lane = tid & 63;
  const int n = qt * 64 + lane;
  const float SCALE = 0.17677669529663687f * 1.4426950408889634f;  // dh^-.5 * log2e
  float* kbuf = smem + w * (2 * TK * 36);
  float* vbuf = kbuf + TK * 36;

  float qr[32];
  {
    const float4* qp = (const float4*)(q + ((size_t)bth * 1024 + n) * 32);
#pragma unroll
    for (int f = 0; f < 8; ++f) {
      float4 tq = qp[f];
      qr[f * 4 + 0] = tq.x * SCALE; qr[f * 4 + 1] = tq.y * SCALE;
      qr[f * 4 + 2] = tq.z * SCALE; qr[f * 4 + 3] = tq.w * SCALE;
    }
  }
  float acc[32];
#pragma unroll
  for (int d = 0; d < 32; ++d) acc[d] = 0.f;
  float mloc = -1e30f, lloc = 0.f;

  const int row = lane >> 1, half = (lane & 1) * 16;
  const size_t kvbase = (size_t)bth * 1024;

#pragma unroll 1
  for (int t = 0; t < 8; ++t) {
    const int key0 = w * 256 + t * TK;
    {
      const float4* kp = (const float4*)(k + (kvbase + key0 + row) * 32 + half);
      const float4* vp = (const float4*)(v + (kvbase + key0 + row) * 32 + half);
      float4* kd = (float4*)&kbuf[row * 36 + half];
      float4* vd = (float4*)&vbuf[row * 36 + half];
#pragma unroll
      for (int f2 = 0; f2 < 4; ++f2) { kd[f2] = kp[f2]; vd[f2] = vp[f2]; }
    }
    __builtin_amdgcn_wave_barrier();  // wave-coherent staging; lgkmcnt dep-waits
    float s[TK];
#pragma unroll
    for (int j = 0; j < TK; ++j) {
      const float4* kr = (const float4*)&kbuf[j * 36];
      float4 k0 = kr[0], k1 = kr[1], k2 = kr[2], k3 = kr[3];
      float4 k4 = kr[4], k5 = kr[5], k6 = kr[6], k7 = kr[7];
      float s0 = qr[0] * k0.x + qr[1] * k0.y + qr[2] * k0.z + qr[3] * k0.w;
      float s1 = qr[4] * k1.x + qr[5] * k1.y + qr[6] * k1.z + qr[7] * k1.w;
      float s2 = qr[8] * k2.x + qr[9] * k2.y + qr[10] * k2.z + qr[11] * k2.w;
      float s3 = qr[12] * k3.x + qr[13] * k3.y + qr[14] * k3.z + qr[15] * k3.w;
      s0 += qr[16] * k4.x + qr[17] * k4.y + qr[18] * k4.z + qr[19] * k4.w;
      s1 += qr[20] * k5.x + qr[21] * k5.y + qr[22] * k5.z + qr[23] * k5.w;
      s2 += qr[24] * k6.x + qr[25] * k6.y + qr[26] * k6.z + qr[27] * k6.w;
      s3 += qr[28] * k7.x + qr[29] * k7.y + qr[30] * k7.z + qr[31] * k7.w;
      s[j] = (s0 + s1) + (s2 + s3);
    }
    float tm = s[0];
#pragma unroll
    for (int j = 1; j < TK; ++j) tm = fmaxf(tm, s[j]);
    const float mnew = fmaxf(mloc, tm);
    const float alpha = __builtin_amdgcn_exp2f(mloc - mnew);
    mloc = mnew;
    lloc *= alpha;
#pragma unroll
    for (int d = 0; d < 32; ++d) acc[d] *= alpha;
#pragma unroll
    for (int j = 0; j < TK; ++j) {
      const float p = __builtin_amdgcn_exp2f(s[j] - mnew);
      lloc += p;
      const float4* vr = (const float4*)&vbuf[j * 36];
#pragma unroll
      for (int f = 0; f < 8; ++f) {
        float4 vv = vr[f];
        acc[f * 4 + 0] += p * vv.x; acc[f * 4 + 1] += p * vv.y;
        acc[f * 4 + 2] += p * vv.z; acc[f * 4 + 3] += p * vv.w;
      }
    }
  }

  // wave 3: local 3x3 neighborhood as one extra masked tile
  if (w == 3) {
    const int pi = n >> 5, pj = n & 31;
    float sl[9];
#pragma unroll
    for (int tt = 0; tt < 9; ++tt) {
      const int ni = pi + tt / 3 - 1;
      const int nj = pj + tt % 3 - 1;
      const bool ok = (ni >= 0) && (ni < 32) && (nj >= 0) && (nj < 32);
      float s = -1e30f;
      if (ok) {
        const float4* kr = (const float4*)(klp + (kvbase + ni * 32 + nj) * 32);
        float s0 = 0.f, s1 = 0.f, s2 = 0.f, s3 = 0.f;
#pragma unroll
        for (int f = 0; f < 8; f += 4) {
          float4 k0 = kr[f], k1 = kr[f + 1], k2 = kr[f + 2], k3 = kr[f + 3];
          s0 += qr[f * 4 + 0] * k0.x + qr[f * 4 + 1] * k0.y + qr[f * 4 + 2] * k0.z + qr[f * 4 + 3] * k0.w;
          s1 += qr[f * 4 + 4] * k1.x + qr[f * 4 + 5] * k1.y + qr[f * 4 + 6] * k1.z + qr[f * 4 + 7] * k1.w;
          s2 += qr[f * 4 + 8] * k2.x + qr[f * 4 + 9] * k2.y + qr[f * 4 + 10] * k2.z + qr[f * 4 + 11] * k2.w;
          s3 += qr[f * 4 + 12] * k3.x + qr[f * 4 + 13] * k3.y + qr[f * 4 + 14] * k3.z + qr[f * 4 + 15] * k3.w;
        }
        s = (s0 + s1) + (s2 + s3);
      }
      sl[tt] = s;
    }
    float tm = sl[0];
#pragma unroll
    for (int tt = 1; tt < 9; ++tt) tm = fmaxf(tm, sl[tt]);
    const float mnew = fmaxf(mloc, tm);
    const float alpha = __builtin_amdgcn_exp2f(mloc - mnew);
    mloc = mnew;
    lloc *= alpha;
#pragma unroll
    for (int d = 0; d < 32; ++d) acc[d] *= alpha;
#pragma unroll
    for (int tt = 0; tt < 9; ++tt) {
      const int ni = pi + tt / 3 - 1;
      const int nj = pj + tt % 3 - 1;
      const bool ok = (ni >= 0) && (ni < 32) && (nj >= 0) && (nj < 32);
      if (ok) {
        const float p = __builtin_amdgcn_exp2f(sl[tt] - mnew);
        lloc += p;
        const float4* vr = (const float4*)(vlp + (kvbase + ni * 32 + nj) * 32);
#pragma unroll
        for (int f = 0; f < 8; ++f) {
          float4 vv = vr[f];
          acc[f * 4 + 0] += p * vv.x; acc[f * 4 + 1] += p * vv.y;
          acc[f * 4 + 2] += p * vv.z; acc[f * 4 + 3] += p * vv.w;
        }
      }
    }
  }

  // merge the 4 split-K partials (online-softmax identity) via LDS
  __syncthreads();
  {
    float* cb = smem + (size_t)(w * 64 + lane) * 35;
    cb[0] = mloc;
    cb[1] = lloc;
#pragma unroll
    for (int d = 0; d < 32; ++d) cb[2 + d] = acc[d];
  }
  __syncthreads();
  if (w == 0) {
    float M = -1e30f, L = 0.f, A[32];
#pragma unroll
    for (int d = 0; d < 32; ++d) A[d] = 0.f;
#pragma unroll
    for (int ww = 0; ww < 4; ++ww) {
      const float* cb = smem + (size_t)(ww * 64 + lane) * 35;
      const float mw = cb[0], lw = cb[1];
      const float Mn = fmaxf(M, mw);
      const float a1 = __builtin_amdgcn_exp2f(M - Mn);
      const float a2 = __builtin_amdgcn_exp2f(mw - Mn);
      L = L * a1 + lw * a2;
#pragma unroll
      for (int d = 0; d < 32; ++d) A[d] = A[d] * a1 + cb[2 + d] * a2;
      M = Mn;
    }
    const float inv = 1.0f / L;
    const int bt = bth >> 3, head = bth & 7;
    float* op = ctx + (((size_t)bt * 1024 + n) * 8 + head) * 32;
#pragma unroll
    for (int f = 0; f < 8; ++f) {
      float4 o;
      o.x = A[f * 4 + 0] * inv; o.y = A[f * 4 + 1] * inv;
      o.z = A[f * 4 + 2] * inv; o.w = A[f * 4 + 3] * inv;
      ((float4*)op)[f] = o;
    }
  }
}

// ---------------------------------------------------------------------------
// K4: out = ctx(8192x256) @ Wo^T, stored as (B, D, T, H*W) with n contiguous.
// ---------------------------------------------------------------------------
__global__ __launch_bounds__(256) void outproj_kernel(const float* __restrict__ ctx,
                                                      const float* __restrict__ Wo,
                                                      float* __restrict__ out) {
  __shared__ float As[16][68];
  __shared__ float Bs[16][68];
  const int m0 = blockIdx.x * 64;
  const int o0 = blockIdx.y * 64;
  const int tid = threadIdx.x;
  const int tx = tid & 15, ty = tid >> 4;
  float c[4][4] = {};
#pragma unroll 1
  for (int k0 = 0; k0 < 256; k0 += 16) {
    const int kb = tid & 15, rb = tid >> 4;
#pragma unroll
    for (int r = 0; r < 4; ++r) {
      As[kb][rb + r * 16] = ctx[(size_t)(m0 + rb + r * 16) * 256 + k0 + kb];
      Bs[kb][rb + r * 16] = Wo[(size_t)(o0 + rb + r * 16) * 256 + k0 + kb];
    }
    __syncthreads();
#pragma unroll
    for (int kk = 0; kk < 16; ++kk) {
      const float4 a4 = *(const float4*)&As[kk][tx * 4];
      const float4 b4 = *(const float4*)&Bs[kk][ty * 4];
      const float a[4] = {a4.x, a4.y, a4.z, a4.w};
      const float b[4] = {b4.x, b4.y, b4.z, b4.w};
#pragma unroll
      for (int i = 0; i < 4; ++i)
#pragma unroll
        for (int j = 0; j < 4; ++j) c[i][j] += a[i] * b[j];
    }
    __syncthreads();
  }
#pragma unroll
  for (int i = 0; i < 4; ++i) {
    const int m = m0 + tx * 4 + i;
    const int bt = m >> 10, n = m & 1023;
    const int b = bt >> 2, t = bt & 3;
#pragma unroll
    for (int j = 0; j < 4; ++j) {
      const int o = o0 + ty * 4 + j;
      out[((size_t)(b * 256 + o) * 4 + t) * 1024 + n] = c[i][j];
    }
  }
}

extern "C" void kernel_launch(void* const* d_in, const int* in_sizes, int n_in,
                              void* d_out, int out_size, void* d_ws, size_t ws_size,
                              hipStream_t stream) {
  const float* x = (const float*)d_in[0];
  const float* gamma = (const float*)d_in[1];
  const float* beta = (const float*)d_in[2];
  const float* Wq = (const float*)d_in[3];
  const float* Wk = (const float*)d_in[4];
  const float* Wv = (const float*)d_in[5];
  const float* Wkl = (const float*)d_in[6];
  const float* Wvl = (const float*)d_in[7];
  const float* Wo = (const float*)d_in[8];
  const float* qb = (const float*)d_in[9];

  float* ws = (float*)d_ws;
  const size_t SZ = (size_t)NROWS * 256;  // 2M floats = 8 MB
  float* xnT = ws;
  float* q = ws + SZ;
  float* k = ws + 2 * SZ;
  float* v = ws + 3 * SZ;
  float* kl = ws + 4 * SZ;
  float* vl = ws + 5 * SZ;
  float* ctx = ws + 6 * SZ;

  hipLaunchKernelGGL(ln_kernel, dim3(128), dim3(256), 0, stream, x, gamma, beta, xnT);
  hipLaunchKernelGGL(proj_kernel, dim3(128, 4, 5), dim3(256), 0, stream, xnT, Wq,
                     Wk, Wv, Wkl, Wvl, qb, q, k, v, kl, vl);
  hipLaunchKernelGGL(attn_kernel, dim3(16, 64), dim3(256), 0, stream, q, k, v, kl,
                     vl, ctx);
  hipLaunchKernelGGL(outproj_kernel, dim3(128, 4), dim3(256), 0, stream, ctx, Wo,
                     (float*)d_out);
}